// Round 2
// baseline (189.999 us; speedup 1.0000x reference)
//
#include <hip/hip_runtime.h>
#include <math.h>

// CBTree contraction, B=4, L=9, d=256.
// g-combine before GEMM (linearity):
//   gL[p]=sum_b lc[b]*h[4p+b], gR[p]=sum_b rc[b]*h[4p+b]
//   h_new[p] = tanh([gL|gR] @ [Wl|Wr].T + vec[p])  (M=n_par, K=512, N=256)
// Round 6: numeric-margin fix on top of round-5 single-pass structure.
// Round 5 failed marginally (absmax 0.0215 vs 0.02 threshold; round 4 passed
// at 0.0195 with 0.0005 margin). Two changes buy ~40% margin:
//   1. fp32 intermediates for L6..L1 outputs (only the 8MB L7 output stays
//      bf16) -> removes child-storage quantization at every level but one.
//   2. split-A: g = g_hi + g_lo (both bf16) in LDS; each B fragment is used
//      twice (acc=mfma(a_hi,b,acc); acc=mfma(a_lo,b,acc)) -> removes
//      g-quantization entirely with ZERO extra B-register pressure.
// Remaining noise: W bf16 quant x4 levels + one bf16 store -> est ~0.013.

typedef __bf16 bf16x8 __attribute__((ext_vector_type(8)));
typedef __bf16 bf16x4 __attribute__((ext_vector_type(4)));
typedef float f32x4 __attribute__((ext_vector_type(4)));

__device__ __forceinline__ float fast_tanh(float x) {
    float ax = fabsf(x);
    float t = __builtin_amdgcn_exp2f(ax * -2.885390082f);  // 2*log2(e)
    float r = (1.0f - t) * __builtin_amdgcn_rcpf(1.0f + t);
    return copysignf(r, x);
}

// ---------------------------------------------------------------------------
// W swizzle: Wfrag holds [Wl|Wr] (N=256 x K=512) in MFMA B-fragment order.
// Fragment (J,T): 64 lanes x 8 bf16; lane L holds B[k=T*32+(L>>4)*8+j][n=J*16+(L&15)]
//   = Wcat[n][k].  Flat: Wfrag[(((J*16)+T)*64 + L)*8 + j]
// ---------------------------------------------------------------------------
__global__ __launch_bounds__(256) void cbt_wconv(
    const float* __restrict__ Wl, const float* __restrict__ Wr,
    __bf16* __restrict__ Wfrag)
{
    const int t = blockIdx.x * 256 + threadIdx.x;   // 0..16383
    const int L = t & 63;
    const int TJ = t >> 6;
    const int T = TJ & 15;
    const int J = TJ >> 4;
    const int n = J * 16 + (L & 15);
    const int k = T * 32 + (L >> 4) * 8;
    const float* src = (k < 256) ? (Wl + (size_t)n * 256 + k)
                                 : (Wr + (size_t)n * 256 + (k - 256));
    const float4 f0 = *reinterpret_cast<const float4*>(src);
    const float4 f1 = *reinterpret_cast<const float4*>(src + 4);
    bf16x8 o;
    o[0] = (__bf16)f0.x; o[1] = (__bf16)f0.y; o[2] = (__bf16)f0.z; o[3] = (__bf16)f0.w;
    o[4] = (__bf16)f1.x; o[5] = (__bf16)f1.y; o[6] = (__bf16)f1.z; o[7] = (__bf16)f1.w;
    *reinterpret_cast<bf16x8*>(Wfrag + (size_t)t * 8) = o;
}

// ---------------------------------------------------------------------------
// MFMA GEMM level kernel, single-pass child reads + split-A.
// Tile 32 x 256 (full N), grid(M/32), 256 threads (4 waves, 2x2).
// Per T-iter (T=0..7): read children cols [T*32,T*32+32) ONCE, build
// {gL_hi,gL_lo,gR_hi,gR_lo} chunks in LDS, then run K-steps T (gL x B-set T)
// and T+8 (gR x B-set T+8), each as hi-MFMA + lo-MFMA reusing the same B.
// B fragment sets double-buffered in registers (L2-resident Wfrag).
// CT = child dtype (float or __bf16), OT = output dtype.
// ---------------------------------------------------------------------------
template <typename CT, typename OT>
__global__ __launch_bounds__(256, 2) void cbt_mfma(
    const CT* __restrict__ h,          // (4*M, 256) children
    const __bf16* __restrict__ Wfrag,  // swizzled weights
    const float* __restrict__ vec,     // (M, 256)
    OT* __restrict__ out)              // (M, 256)
{
    // rows of 32 bf16, stride 40 (80B) -> <=2-way bank aliasing on b128 reads
    // regions: gL_hi @0, gL_lo @1280, gR_hi @2560, gR_lo @3840 (elements)
    __shared__ __align__(16) __bf16 Alds[4 * 32 * 40];

    const int tid = threadIdx.x;
    const int lane = tid & 63;
    const int w = tid >> 6;
    const int wr = w >> 1, wc = w & 1;        // wave tile: rows wr*16, cols wc*128
    const int mBase = blockIdx.x * 32;

    f32x4 acc[8] = {};

    // A staging: 8 threads per parent row, 4 cols each
    const int sm  = tid >> 3;                 // parent row 0..31
    const int skq = (tid & 7) * 4;            // col offset 0..28
    const CT* hb = h + (size_t)(mBase + sm) * 1024 + skq;

    float c0[4], c1[4], c2[4], c3[4];
    auto load_h = [&](int k0) {
        if constexpr (sizeof(CT) == 4) {      // fp32 children
            const float4 a = *reinterpret_cast<const float4*>(hb + k0);
            const float4 b = *reinterpret_cast<const float4*>(hb + k0 + 256);
            const float4 c = *reinterpret_cast<const float4*>(hb + k0 + 512);
            const float4 d = *reinterpret_cast<const float4*>(hb + k0 + 768);
            c0[0] = a.x; c0[1] = a.y; c0[2] = a.z; c0[3] = a.w;
            c1[0] = b.x; c1[1] = b.y; c1[2] = b.z; c1[3] = b.w;
            c2[0] = c.x; c2[1] = c.y; c2[2] = c.z; c2[3] = c.w;
            c3[0] = d.x; c3[1] = d.y; c3[2] = d.z; c3[3] = d.w;
        } else {                              // bf16 children
            const bf16x4 a = *reinterpret_cast<const bf16x4*>(hb + k0);
            const bf16x4 b = *reinterpret_cast<const bf16x4*>(hb + k0 + 256);
            const bf16x4 c = *reinterpret_cast<const bf16x4*>(hb + k0 + 512);
            const bf16x4 d = *reinterpret_cast<const bf16x4*>(hb + k0 + 768);
#pragma unroll
            for (int j = 0; j < 4; ++j) {
                c0[j] = (float)a[j]; c1[j] = (float)b[j];
                c2[j] = (float)c[j]; c3[j] = (float)d[j];
            }
        }
    };

    auto store_A = [&]() {
        constexpr float C23 = 2.0f / 3.0f, C13 = 1.0f / 3.0f;
        bf16x4 glh, gll, grh, grl;
#pragma unroll
        for (int j = 0; j < 4; ++j) {
            const float gl = c0[j] + C23 * c1[j] + C13 * c2[j];
            const float gr = C13 * c1[j] + C23 * c2[j] + c3[j];
            glh[j] = (__bf16)gl;
            gll[j] = (__bf16)(gl - (float)glh[j]);
            grh[j] = (__bf16)gr;
            grl[j] = (__bf16)(gr - (float)grh[j]);
        }
        const int o = sm * 40 + skq;
        *reinterpret_cast<bf16x4*>(&Alds[o])        = glh;
        *reinterpret_cast<bf16x4*>(&Alds[o + 1280]) = gll;
        *reinterpret_cast<bf16x4*>(&Alds[o + 2560]) = grh;
        *reinterpret_cast<bf16x4*>(&Alds[o + 3840]) = grl;
    };

    // B fragments: buf0 = gL sets (K-steps 0..7), buf1 = gR sets (8..15),
    // each prefetched one full iteration ahead (L2-hot Wfrag).
    bf16x8 bfr[2][8];
    const __bf16* Wb = Wfrag + ((size_t)wc * 128 * 64 + lane) * 8;  // J0=wc*8
    auto load_B = [&](int s, int buf) {
        const __bf16* p = Wb + (size_t)s * 512;
#pragma unroll
        for (int j = 0; j < 8; ++j)
            bfr[buf][j] = *reinterpret_cast<const bf16x8*>(p + (size_t)j * 8192);
    };

    load_h(0);
    load_B(0, 0);
    load_B(8, 1);

    const int arow = (wr * 16 + (lane & 15)) * 40 + (lane >> 4) * 8;

    for (int T = 0; T < 8; ++T) {
        __syncthreads();              // all waves done with previous A tile
        store_A();
        __syncthreads();

        if (T < 7) load_h((T + 1) * 32);   // prefetch next child chunk

        const bf16x8 afLh = *reinterpret_cast<const bf16x8*>(&Alds[arow]);
        const bf16x8 afLl = *reinterpret_cast<const bf16x8*>(&Alds[arow + 1280]);
#pragma unroll
        for (int j = 0; j < 8; ++j)
            acc[j] = __builtin_amdgcn_mfma_f32_16x16x32_bf16(
                afLh, bfr[0][j], acc[j], 0, 0, 0);
#pragma unroll
        for (int j = 0; j < 8; ++j)
            acc[j] = __builtin_amdgcn_mfma_f32_16x16x32_bf16(
                afLl, bfr[0][j], acc[j], 0, 0, 0);

        if (T < 7) load_B(T + 1, 0);       // next gL B-set

        const bf16x8 afRh = *reinterpret_cast<const bf16x8*>(&Alds[arow + 2560]);
        const bf16x8 afRl = *reinterpret_cast<const bf16x8*>(&Alds[arow + 3840]);
#pragma unroll
        for (int j = 0; j < 8; ++j)
            acc[j] = __builtin_amdgcn_mfma_f32_16x16x32_bf16(
                afRh, bfr[1][j], acc[j], 0, 0, 0);
#pragma unroll
        for (int j = 0; j < 8; ++j)
            acc[j] = __builtin_amdgcn_mfma_f32_16x16x32_bf16(
                afRl, bfr[1][j], acc[j], 0, 0, 0);

        if (T < 7) load_B(T + 9, 1);       // next gR B-set
    }

    // epilogue: C/D layout col=lane&15, row=(lane>>4)*4+reg
    const int q = lane >> 4, n16 = lane & 15;
    const int mrow = mBase + wr * 16 + q * 4;
#pragma unroll
    for (int j = 0; j < 8; ++j) {
        const int n = wc * 128 + j * 16 + n16;
#pragma unroll
        for (int r = 0; r < 4; ++r) {
            const size_t idx = (size_t)(mrow + r) * 256 + n;
            out[idx] = (OT)fast_tanh(acc[j][r] + vec[idx]);
        }
    }
}

// ---------------------------------------------------------------------------
// Tiny levels (M <= 64): one wave per output element, fully fp32 (exact):
// fp32 children, fp32 W, fp32 out.  grid = M*64 blocks of 256 (4 waves).
// ---------------------------------------------------------------------------
__global__ __launch_bounds__(256) void cbt_small(
    const float* __restrict__ h, const float* __restrict__ Wl,
    const float* __restrict__ Wr, const float* __restrict__ vec,
    float* __restrict__ out)
{
    const int w = blockIdx.x * 4 + (threadIdx.x >> 6);
    const int lane = threadIdx.x & 63;
    const int m = w >> 8;
    const int n = w & 255;

    const float* hbp = h + (size_t)m * 1024 + lane * 4;
    const float4 c0 = *reinterpret_cast<const float4*>(hbp);
    const float4 c1 = *reinterpret_cast<const float4*>(hbp + 256);
    const float4 c2 = *reinterpret_cast<const float4*>(hbp + 512);
    const float4 c3 = *reinterpret_cast<const float4*>(hbp + 768);
    const float4 wl = *reinterpret_cast<const float4*>(Wl + (size_t)n * 256 + lane * 4);
    const float4 wr = *reinterpret_cast<const float4*>(Wr + (size_t)n * 256 + lane * 4);

    constexpr float C23 = 2.0f / 3.0f;
    constexpr float C13 = 1.0f / 3.0f;
    const float f0[4] = {c0.x, c0.y, c0.z, c0.w};
    const float f1[4] = {c1.x, c1.y, c1.z, c1.w};
    const float f2[4] = {c2.x, c2.y, c2.z, c2.w};
    const float f3[4] = {c3.x, c3.y, c3.z, c3.w};
    const float wlv[4] = {wl.x, wl.y, wl.z, wl.w};
    const float wrv[4] = {wr.x, wr.y, wr.z, wr.w};
    float acc = 0.0f;
#pragma unroll
    for (int j = 0; j < 4; ++j) {
        const float gl = f0[j] + C23 * f1[j] + C13 * f2[j];
        const float gr = C13 * f1[j] + C23 * f2[j] + f3[j];
        acc += gl * wlv[j] + gr * wrv[j];
    }
#pragma unroll
    for (int off = 32; off >= 1; off >>= 1) acc += __shfl_xor(acc, off, 64);

    if (lane == 0)
        out[(size_t)m * 256 + n] = fast_tanh(acc + vec[(size_t)m * 256 + n]);
}

// ---------------------------------------------------------------------------
extern "C" void kernel_launch(void* const* d_in, const int* in_sizes, int n_in,
                              void* d_out, int out_size, void* d_ws, size_t ws_size,
                              hipStream_t stream) {
    const float* vectors = (const float*)d_in[0];
    const float* Wl = (const float*)d_in[1];
    const float* Wr = (const float*)d_in[2];

    // ws layout:
    //   buf7  bf16  16384x256 (8 MB)   L7 out
    //   buf6  f32    4096x256 (4 MB)   L6 out
    //   buf5  f32    1024x256 (1 MB)   L5 out
    //   buf4  f32     256x256 (256 KB) L4 out
    //   buf3  f32      64x256 (64 KB)  L3 out
    //   buf2  f32      16x256 (16 KB)  L2 out
    //   buf1  f32       4x256 (4 KB)   L1 out
    //   Wfrag bf16  16384x8   (256 KB)
    // total ~13.6 MB
    char* p = (char*)d_ws;
    __bf16* buf7 = (__bf16*)p;           p += (size_t)16384 * 256 * 2;
    float*  buf6 = (float*)p;            p += (size_t)4096 * 256 * 4;
    float*  buf5 = (float*)p;            p += (size_t)1024 * 256 * 4;
    float*  buf4 = (float*)p;            p += (size_t)256 * 256 * 4;
    float*  buf3 = (float*)p;            p += (size_t)64 * 256 * 4;
    float*  buf2 = (float*)p;            p += (size_t)16 * 256 * 4;
    float*  buf1 = (float*)p;            p += (size_t)4 * 256 * 4;
    __bf16* Wfrag = (__bf16*)p;

    size_t offsets[10];
    offsets[0] = 0;
    size_t sz = 1;
    for (int l = 0; l < 9; ++l) { offsets[l + 1] = offsets[l] + sz; sz *= 4; }

    // weight swizzle (no dependency on h levels)
    hipLaunchKernelGGL(cbt_wconv, dim3(64), dim3(256), 0, stream, Wl, Wr, Wfrag);

    const float* leaf = vectors + offsets[8] * 256;

    // L7: fp32 leaves -> bf16 out (8MB), M=16384: 512 blocks (2/CU)
    hipLaunchKernelGGL((cbt_mfma<float, __bf16>), dim3(512), dim3(256), 0, stream,
                       leaf, Wfrag, vectors + offsets[7] * 256, buf7);
    // L6: bf16 children -> fp32 out, M=4096: 128 blocks
    hipLaunchKernelGGL((cbt_mfma<__bf16, float>), dim3(128), dim3(256), 0, stream,
                       buf7, Wfrag, vectors + offsets[6] * 256, buf6);
    // L5: fp32 -> fp32, M=1024: 32 blocks
    hipLaunchKernelGGL((cbt_mfma<float, float>), dim3(32), dim3(256), 0, stream,
                       buf6, Wfrag, vectors + offsets[5] * 256, buf5);
    // L4: fp32 -> fp32, M=256: 8 blocks
    hipLaunchKernelGGL((cbt_mfma<float, float>), dim3(8), dim3(256), 0, stream,
                       buf5, Wfrag, vectors + offsets[4] * 256, buf4);
    // L3..L0: wave-per-output, fully fp32
    hipLaunchKernelGGL(cbt_small, dim3(64 * 64), dim3(256), 0, stream,
                       buf4, Wl, Wr, vectors + offsets[3] * 256, buf3);
    hipLaunchKernelGGL(cbt_small, dim3(16 * 64), dim3(256), 0, stream,
                       buf3, Wl, Wr, vectors + offsets[2] * 256, buf2);
    hipLaunchKernelGGL(cbt_small, dim3(4 * 64), dim3(256), 0, stream,
                       buf2, Wl, Wr, vectors + offsets[1] * 256, buf1);
    hipLaunchKernelGGL(cbt_small, dim3(1 * 64), dim3(256), 0, stream,
                       buf1, Wl, Wr, vectors + offsets[0] * 256, (float*)d_out);
}